// Round 1
// baseline (363.803 us; speedup 1.0000x reference)
//
#include <hip/hip_runtime.h>
#include <math.h>

// Problem constants
#define V_ 25
#define C_ 64
#define D_ 64
#define N_ 64
#define T_ 300
#define R_ (N_*T_)      // 19200 rows
#define K_ (V_*C_)      // 1600
#define BN_EPS 1e-5f

// Workspace layout (4-byte units)
#define WS_GM     0      // (bf16(mask)<<16) | lds_off, k order     [1600] u32
#define WS_SCALE  1600   // BN scale, OUTPUT order kk=dd*25+v       [1600] f32
#define WS_SHIFT  3200   // BN shift, OUTPUT order kk               [1600] f32
#define WS_VP     4800   // s_out jj, OUTPUT order kk               [1600] i32
#define WS_SUM    6400   // sum_y per (v,d) flat jj                 [1600] f32
#define WS_SQ     8000   // sumsq_y per (v,d) flat jj (contig!)     [1600] f32
#define WS_WBF    9600   // W as bf16                               [4096] u16

// pass1 partials live in d_out (overwritten by pass2 afterwards):
// P[b][j], b in [0,2400), j in [0,3200): j<1600 sums, else sqs.
#define P1_BLOCKS 2400   // 8 rows each, 2 windows of 4

using bf16x8 = __attribute__((ext_vector_type(8))) short;
using f32x4  = __attribute__((ext_vector_type(4))) float;

__device__ __forceinline__ unsigned short f2bf(float f) {
    unsigned u = __float_as_uint(f);
    return (unsigned short)((u + 0x7FFFu + ((u >> 16) & 1u)) >> 16);
}

// ---------- prep: combined mask/offset table (k order) + bf16 W ----------
__global__ __launch_bounds__(256) void prep_tables(
    const float* __restrict__ fm, const float* __restrict__ W,
    const int* __restrict__ s_in, float* __restrict__ ws)
{
    int idx = blockIdx.x * 256 + threadIdx.x;   // 16 blocks -> 4096
    if (idx < K_) {
        int jj  = s_in[idx];
        int off = (jj & 63) * 100 + (jj >> 6);          // LDS offset, fits 16 bits
        unsigned mk = (unsigned)f2bf(tanhf(fm[idx]) + 1.0f);
        ((unsigned*)ws)[WS_GM + idx] = (mk << 16) | (unsigned)off;
    }
    if (idx < C_ * D_) ((unsigned short*)(ws + WS_WBF))[idx] = f2bf(W[idx]);
}

// ---------- reduce per-block partials (from d_out scratch) into WS_SUM/WS_SQ ----
// grid 200 x 256: block handles 16 columns; 16-way row split x 150 rows each.
__global__ __launch_bounds__(256) void stats_reduce(
    const float* __restrict__ pbuf, float* __restrict__ ws)
{
    __shared__ float red[256];
    int jq = threadIdx.x & 15;
    int bq = threadIdx.x >> 4;              // 0..15
    int j  = blockIdx.x * 16 + jq;          // 200*16 = 3200 columns
    const float* p = pbuf + (size_t)(bq * 150) * 3200 + j;
    float s = 0.f;
    #pragma unroll 10
    for (int k = 0; k < 150; ++k)
        s += p[(size_t)k * 3200];
    red[threadIdx.x] = s;
    __syncthreads();
    if (bq < 8) red[threadIdx.x] += red[threadIdx.x + 128];
    __syncthreads();
    if (bq < 4) red[threadIdx.x] += red[threadIdx.x + 64];
    __syncthreads();
    if (bq < 2) red[threadIdx.x] += red[threadIdx.x + 32];
    __syncthreads();
    if (bq == 0) ws[WS_SUM + j] = red[jq] + red[jq + 16];
}

// ---------- prep: BN scale/shift + shift_out table, OUTPUT order ----------
__global__ __launch_bounds__(256) void prep_scale_kernel(
    const float* __restrict__ gamma, const float* __restrict__ beta,
    const int* __restrict__ s_out, float* __restrict__ ws)
{
    int kk = blockIdx.x * 256 + threadIdx.x;    // kk = dd*25 + v
    if (kk < K_) {
        int dd = kk / 25;
        int v  = kk - dd * 25;
        int k  = v * 64 + dd;
        int jj = s_out[k];
        float mean = ws[WS_SUM + jj] * (1.0f / (float)R_);
        float var  = fmaf(-mean, mean, ws[WS_SQ + jj] * (1.0f / (float)R_));
        float inv  = rsqrtf(var + BN_EPS);
        float sc   = gamma[k] * inv;
        ws[WS_SCALE + kk] = sc;
        ws[WS_SHIFT + kk] = beta[k] - mean * sc;
        ((int*)ws)[WS_VP + kk] = jj;
    }
}

// Stage the 4-row window into LDS with coalesced float4 loads.
// xs[c*100 + dt*25 + v] = x0[n, c, t0+dt, v]. 1600 float4 total.
__device__ __forceinline__ void stage_xs(
    const float* __restrict__ xwin, float4* xs4, int tid)
{
    const float4* s4 = (const float4*)xwin;     // t0 % 4 == 0 -> 16B aligned
    #pragma unroll
    for (int i = 0; i < 7; ++i) {
        int idx = i * 256 + tid;
        if (idx < 1600) {
            int c = idx / 25;
            int r = idx - c * 25;
            xs4[c * 25 + r] = s4[c * 1875 + r];
        }
    }
}

// T14 split staging: issue window loads into regs (early) ...
__device__ __forceinline__ void load_window_regs(
    const float* __restrict__ xwin, float4 pf[7], int tid)
{
    const float4* s4 = (const float4*)xwin;
    #pragma unroll
    for (int i = 0; i < 7; ++i) {
        int idx = i * 256 + tid;
        if (idx < 1600) {
            int c = idx / 25;
            int r = idx - c * 25;
            pf[i] = s4[c * 1875 + r];
        }
    }
}
// ... and commit regs -> LDS (late, after latency hidden under build+MFMA).
__device__ __forceinline__ void store_window_regs(
    const float4 pf[7], float4* xs4, int tid)
{
    #pragma unroll
    for (int i = 0; i < 7; ++i) {
        int idx = i * 256 + tid;
        if (idx < 1600) {
            int c = idx / 25;
            int r = idx - c * 25;
            xs4[c * 25 + r] = pf[i];
        }
    }
}

// Preload this thread's 28 gather-table entries (same for every window).
__device__ __forceinline__ void load_gmr(
    const unsigned* __restrict__ gmt, unsigned gmr[28], int lane, int w)
{
    int jw = lane & 3;
    int vh = lane >> 4;             // m>>2 where m=lane>>2
    #pragma unroll
    for (int i = 0; i < 14; ++i) {
        int combo = i * 4 + w;      // (T,q2)
        int T  = combo >> 2;
        int q2 = combo & 3;
        int t  = T >> 1;
        int c0 = (T & 1) * 32 + q2 * 8 + jw * 2;
        int v  = t * 4 + vh;
        int kb = (v < V_) ? (v * 64 + c0) : c0;   // clamp padded rows
        gmr[2 * i]     = gmt[kb];
        gmr[2 * i + 1] = gmt[kb + 1];
    }
}

// Build fragment-major bf16 A buffer from staged xs. Same a_fm layout/semantics
// as verified baseline: word (T*64+q2*16+m)*4+jw.
__device__ __forceinline__ void build_afm(
    const float* xs, unsigned* a_fm32, const unsigned gmr[28], int lane, int w)
{
    int m  = lane >> 2;
    int jw = lane & 3;
    int dt = m & 3;
    #pragma unroll
    for (int i = 0; i < 14; ++i) {
        int combo = i * 4 + w;
        int T  = combo >> 2;
        int q2 = combo & 3;
        unsigned g0 = gmr[2 * i], g1 = gmr[2 * i + 1];
        float m0 = __uint_as_float(g0 & 0xFFFF0000u);
        float m1 = __uint_as_float(g1 & 0xFFFF0000u);
        float f0 = xs[(g0 & 0xFFFFu) + dt * 25] * m0;
        float f1 = xs[(g1 & 0xFFFFu) + dt * 25] * m1;
        a_fm32[(T * 64 + q2 * 16 + m) * 4 + jw] =
            (unsigned)f2bf(f0) | ((unsigned)f2bf(f1) << 16);
    }
}

// ---------- pass 1: BN statistics (8 rows = 2 windows per block) ----------
// No atomics: per-block partial sums stored to pbuf (= d_out scratch).
__global__ __launch_bounds__(256, 4) void pass1_stats(
    const float* __restrict__ x0, const float* __restrict__ bg,
    const float* __restrict__ ws, float* __restrict__ pbuf)
{
    __shared__ __align__(16) float4 xs4[1600];            // 25600 B
    __shared__ __align__(16) unsigned a_fm32[3584];       // 14336 B
    const float* xs = (const float*)xs4;
    const bf16x8* afp = (const bf16x8*)a_fm32;

    int tid = threadIdx.x;
    int lane = tid & 63, w = tid >> 6;
    int l15 = lane & 15, q = lane >> 4;
    int d = w * 16 + l15;

    const unsigned short* Wbf = (const unsigned short*)(ws + WS_WBF);
    bf16x8 bfrag0, bfrag1;
    #pragma unroll
    for (int j = 0; j < 8; ++j) {
        bfrag0[j] = (short)Wbf[(q * 8 + j) * 64 + d];
        bfrag1[j] = (short)Wbf[(32 + q * 8 + j) * 64 + d];
    }
    float breg = bg[d];

    unsigned gmr[28];
    load_gmr((const unsigned*)ws + WS_GM, gmr, lane, w);

    float sums[7], sqs[7];
    #pragma unroll
    for (int t = 0; t < 7; ++t) { sums[t] = 0.f; sqs[t] = 0.f; }

    int r0base = blockIdx.x * 8;
    float4 pf[7];
    {   // prologue: window 0
        int r0 = r0base;
        int n  = r0 / 300;
        int t0 = r0 - n * 300;              // 4 | 300 -> n uniform in window
        load_window_regs(x0 + (size_t)n * 480000 + t0 * 25, pf, tid);
        store_window_regs(pf, xs4, tid);
    }
    __syncthreads();

    #pragma unroll 1
    for (int st = 0; st < 2; ++st) {
        if (st < 1) {                        // issue next window's loads early
            int r0 = r0base + 4;
            int n  = r0 / 300;
            int t0 = r0 - n * 300;
            load_window_regs(x0 + (size_t)n * 480000 + t0 * 25, pf, tid);
        }
        build_afm(xs, a_fm32, gmr, lane, w);
        __syncthreads();                     // a_fm ready; xs reads done

        #pragma unroll
        for (int t = 0; t < 7; ++t) {
            bf16x8 a0 = afp[(t * 2 + 0) * 64 + lane];
            bf16x8 a1 = afp[(t * 2 + 1) * 64 + lane];
            f32x4 acc = {0.f, 0.f, 0.f, 0.f};
            acc = __builtin_amdgcn_mfma_f32_16x16x32_bf16(a0, bfrag0, acc, 0, 0, 0);
            acc = __builtin_amdgcn_mfma_f32_16x16x32_bf16(a1, bfrag1, acc, 0, 0, 0);
            #pragma unroll
            for (int r = 0; r < 4; ++r) {
                float y = acc[r] + breg;
                sums[t] += y;
                sqs[t]   = fmaf(y, y, sqs[t]);
            }
        }

        if (st < 1) store_window_regs(pf, xs4, tid);  // commit: latency hidden
        __syncthreads();                     // a_fm free + new xs visible
    }

    // per-block partials, non-atomic, coalesced 64B segments
    float* pout = pbuf + (size_t)blockIdx.x * 3200;
    #pragma unroll
    for (int t = 0; t < 7; ++t) {
        int v = t * 4 + q;              // C-layout: row quad == v within tile
        if (v < V_) {
            pout[v * 64 + d]        = sums[t];
            pout[1600 + v * 64 + d] = sqs[t];
        }
    }
}

// ---------- pass 2: recompute y, shift_out, BN affine, residual, ReLU ----------
__global__ __launch_bounds__(256, 4) void pass2_out(
    const float* __restrict__ x0, const float* __restrict__ bg,
    const float* __restrict__ ws, float* __restrict__ out)
{
    // xs (25600 B) and y_lds (25600 B) are time-disjoint -> union. +a_fm 14336.
    __shared__ __align__(16) char smem[25600 + 14336];    // 39936 B
    float4* xs4   = (float4*)smem;
    const float* xs = (const float*)smem;
    float* y_lds  = (float*)smem;                          // [d][dt*25 + v]
    unsigned* a_fm32 = (unsigned*)(smem + 25600);
    const bf16x8* afp = (const bf16x8*)a_fm32;

    int tid = threadIdx.x;
    int lane = tid & 63, w = tid >> 6;
    int l15 = lane & 15, q = lane >> 4;
    int d = w * 16 + l15;

    const unsigned short* Wbf = (const unsigned short*)(ws + WS_WBF);
    bf16x8 bfrag0, bfrag1;
    #pragma unroll
    for (int j = 0; j < 8; ++j) {
        bfrag0[j] = (short)Wbf[(q * 8 + j) * 64 + d];
        bfrag1[j] = (short)Wbf[(32 + q * 8 + j) * 64 + d];
    }
    float breg = bg[d];

    unsigned gmr[28];
    load_gmr((const unsigned*)ws + WS_GM, gmr, lane, w);

    int r0 = blockIdx.x * 4;
    int n  = r0 / 300;
    int t0 = r0 - n * 300;
    const float* xwin = x0 + (size_t)n * 480000 + t0 * 25;

    stage_xs(xwin, xs4, tid);
    __syncthreads();
    build_afm(xs, a_fm32, gmr, lane, w);
    __syncthreads();                    // xs dead from here; y_lds takes over

    #pragma unroll
    for (int t = 0; t < 7; ++t) {
        bf16x8 a0 = afp[(t * 2 + 0) * 64 + lane];
        bf16x8 a1 = afp[(t * 2 + 1) * 64 + lane];
        f32x4 acc = {0.f, 0.f, 0.f, 0.f};
        acc = __builtin_amdgcn_mfma_f32_16x16x32_bf16(a0, bfrag0, acc, 0, 0, 0);
        acc = __builtin_amdgcn_mfma_f32_16x16x32_bf16(a1, bfrag1, acc, 0, 0, 0);
        int v = t * 4 + q;
        if (v < V_) {
            // y[v, dt=r, d]: bank stride 4 per l15, exact 2-way across wave: free
            #pragma unroll
            for (int r = 0; r < 4; ++r)
                y_lds[d * 100 + r * 25 + v] = acc[r] + breg;
        }
    }
    __syncthreads();

    const float* scp = ws + WS_SCALE;
    const float* shp = ws + WS_SHIFT;
    const int*   vpp = (const int*)ws + WS_VP;
    #pragma unroll
    for (int i = 0; i < 25; ++i) {        // 25*256 = 6400 outputs
        int e   = i * 256 + tid;
        int dd  = e / 100;
        int rem = e - dd * 100;
        int dt  = rem / 25;
        int v   = rem - dt * 25;
        int kk  = dd * 25 + v;            // tables in output order: coalesced
        int jj  = vpp[kk];
        float z = y_lds[(jj & 63) * 100 + dt * 25 + (jj >> 6)];
        int ga  = (n * 64 + dd) * 7500 + (t0 + dt) * 25 + v;
        float val = fmaf(z, scp[kk], shp[kk]) + x0[ga];   // residual: L2-warm
        __builtin_nontemporal_store(fmaxf(val, 0.f), &out[ga]);
    }
}

extern "C" void kernel_launch(void* const* d_in, const int* in_sizes, int n_in,
                              void* d_out, int out_size, void* d_ws, size_t ws_size,
                              hipStream_t stream)
{
    const float* x0    = (const float*)d_in[0];
    const float* fm    = (const float*)d_in[1];
    const float* W     = (const float*)d_in[2];
    const float* b     = (const float*)d_in[3];
    const float* gamma = (const float*)d_in[4];
    const float* beta  = (const float*)d_in[5];
    const int*   s_in  = (const int*)d_in[6];
    const int*   s_out = (const int*)d_in[7];
    float* out = (float*)d_out;
    float* ws  = (float*)d_ws;

    prep_tables<<<16, 256, 0, stream>>>(fm, W, s_in, ws);
    // pass1 scribbles partials into d_out; pass2 fully overwrites it afterwards.
    pass1_stats<<<P1_BLOCKS, 256, 0, stream>>>(x0, b, ws, out);
    stats_reduce<<<200, 256, 0, stream>>>(out, ws);
    prep_scale_kernel<<<7, 256, 0, stream>>>(gamma, beta, s_out, ws);
    pass2_out<<<R_ / 4, 256, 0, stream>>>(x0, b, ws, out);
}

// Round 2
// 309.705 us; speedup vs baseline: 1.1747x; 1.1747x over previous
//
#include <hip/hip_runtime.h>
#include <math.h>

// Problem constants
#define V_ 25
#define C_ 64
#define D_ 64
#define N_ 64
#define T_ 300
#define R_ (N_*T_)      // 19200 rows
#define K_ (V_*C_)      // 1600
#define BN_EPS 1e-5f

// Workspace layout (4-byte units)
#define WS_GM     0      // (bf16(mask)<<16) | lds_off, k order     [1600] u32
#define WS_SCALE  1600   // BN scale, OUTPUT order kk=dd*25+v       [1600] f32
#define WS_SHIFT  3200   // BN shift, OUTPUT order kk               [1600] f32
#define WS_VP     4800   // s_out jj, OUTPUT order kk               [1600] i32
#define WS_SUM    6400   // sum_y per (v,d) flat jj                 [1600] f32
#define WS_SQ     8000   // sumsq_y per (v,d) flat jj (contig!)     [1600] f32
#define WS_WBF    9600   // W as bf16                               [4096] u16

// pass1 partials live in d_out (overwritten by pass2 afterwards):
// P[b][j], b in [0,1200), j in [0,3200): j<1600 sums, else sqs.
#define P1_BLOCKS 1200   // 16 rows each, 4 windows of 4 (round-0 structure)

using bf16x8 = __attribute__((ext_vector_type(8))) short;
using f32x4  = __attribute__((ext_vector_type(4))) float;

__device__ __forceinline__ unsigned short f2bf(float f) {
    unsigned u = __float_as_uint(f);
    return (unsigned short)((u + 0x7FFFu + ((u >> 16) & 1u)) >> 16);
}

// ---------- prep: combined mask/offset table (k order) + bf16 W ----------
__global__ __launch_bounds__(256) void prep_tables(
    const float* __restrict__ fm, const float* __restrict__ W,
    const int* __restrict__ s_in, float* __restrict__ ws)
{
    int idx = blockIdx.x * 256 + threadIdx.x;   // 16 blocks -> 4096
    if (idx < K_) {
        int jj  = s_in[idx];
        int off = (jj & 63) * 100 + (jj >> 6);          // LDS offset, fits 16 bits
        unsigned mk = (unsigned)f2bf(tanhf(fm[idx]) + 1.0f);
        ((unsigned*)ws)[WS_GM + idx] = (mk << 16) | (unsigned)off;
    }
    if (idx < C_ * D_) ((unsigned short*)(ws + WS_WBF))[idx] = f2bf(W[idx]);
}

// ---------- reduce per-block partials (from d_out scratch) into WS_SUM/WS_SQ ----
// grid 200 x 256: block handles 16 columns; 16-way row split x 75 rows each.
__global__ __launch_bounds__(256) void stats_reduce(
    const float* __restrict__ pbuf, float* __restrict__ ws)
{
    __shared__ float red[256];
    int jq = threadIdx.x & 15;
    int bq = threadIdx.x >> 4;              // 0..15
    int j  = blockIdx.x * 16 + jq;          // 200*16 = 3200 columns
    const float* p = pbuf + (size_t)(bq * 75) * 3200 + j;
    float s = 0.f;
    #pragma unroll 5
    for (int k = 0; k < 75; ++k)
        s += p[(size_t)k * 3200];
    red[threadIdx.x] = s;
    __syncthreads();
    if (bq < 8) red[threadIdx.x] += red[threadIdx.x + 128];
    __syncthreads();
    if (bq < 4) red[threadIdx.x] += red[threadIdx.x + 64];
    __syncthreads();
    if (bq < 2) red[threadIdx.x] += red[threadIdx.x + 32];
    __syncthreads();
    if (bq == 0) ws[WS_SUM + j] = red[jq] + red[jq + 16];
}

// ---------- prep: BN scale/shift + shift_out table, OUTPUT order ----------
__global__ __launch_bounds__(256) void prep_scale_kernel(
    const float* __restrict__ gamma, const float* __restrict__ beta,
    const int* __restrict__ s_out, float* __restrict__ ws)
{
    int kk = blockIdx.x * 256 + threadIdx.x;    // kk = dd*25 + v
    if (kk < K_) {
        int dd = kk / 25;
        int v  = kk - dd * 25;
        int k  = v * 64 + dd;
        int jj = s_out[k];
        float mean = ws[WS_SUM + jj] * (1.0f / (float)R_);
        float var  = fmaf(-mean, mean, ws[WS_SQ + jj] * (1.0f / (float)R_));
        float inv  = rsqrtf(var + BN_EPS);
        float sc   = gamma[k] * inv;
        ws[WS_SCALE + kk] = sc;
        ws[WS_SHIFT + kk] = beta[k] - mean * sc;
        ((int*)ws)[WS_VP + kk] = jj;
    }
}

// Stage the 4-row window into LDS with coalesced float4 loads.
// xs[c*100 + dt*25 + v] = x0[n, c, t0+dt, v]. 1600 float4 total.
__device__ __forceinline__ void stage_xs(
    const float* __restrict__ xwin, float4* xs4, int tid)
{
    const float4* s4 = (const float4*)xwin;     // t0 % 4 == 0 -> 16B aligned
    #pragma unroll
    for (int i = 0; i < 7; ++i) {
        int idx = i * 256 + tid;
        if (idx < 1600) {
            int c = idx / 25;
            int r = idx - c * 25;
            xs4[c * 25 + r] = s4[c * 1875 + r];
        }
    }
}

// Preload this thread's 28 gather-table entries (same for every window).
__device__ __forceinline__ void load_gmr(
    const unsigned* __restrict__ gmt, unsigned gmr[28], int lane, int w)
{
    int jw = lane & 3;
    int vh = lane >> 4;             // m>>2 where m=lane>>2
    #pragma unroll
    for (int i = 0; i < 14; ++i) {
        int combo = i * 4 + w;      // (T,q2)
        int T  = combo >> 2;
        int q2 = combo & 3;
        int t  = T >> 1;
        int c0 = (T & 1) * 32 + q2 * 8 + jw * 2;
        int v  = t * 4 + vh;
        int kb = (v < V_) ? (v * 64 + c0) : c0;   // clamp padded rows
        gmr[2 * i]     = gmt[kb];
        gmr[2 * i + 1] = gmt[kb + 1];
    }
}

// Build fragment-major bf16 A buffer from staged xs. Same a_fm layout/semantics
// as verified baseline: word (T*64+q2*16+m)*4+jw, bank == lane&31 on writes.
__device__ __forceinline__ void build_afm(
    const float* xs, unsigned* a_fm32, const unsigned gmr[28], int lane, int w)
{
    int m  = lane >> 2;
    int jw = lane & 3;
    int dt = m & 3;
    #pragma unroll
    for (int i = 0; i < 14; ++i) {
        int combo = i * 4 + w;
        int T  = combo >> 2;
        int q2 = combo & 3;
        unsigned g0 = gmr[2 * i], g1 = gmr[2 * i + 1];
        float m0 = __uint_as_float(g0 & 0xFFFF0000u);
        float m1 = __uint_as_float(g1 & 0xFFFF0000u);
        float f0 = xs[(g0 & 0xFFFFu) + dt * 25] * m0;
        float f1 = xs[(g1 & 0xFFFFu) + dt * 25] * m1;
        a_fm32[(T * 64 + q2 * 16 + m) * 4 + jw] =
            (unsigned)f2bf(f0) | ((unsigned)f2bf(f1) << 16);
    }
}

// ---------- pass 1: BN statistics (16 rows = 4 windows per block) ----------
// Round-0 structure (direct stage, no reg prefetch); atomic tail replaced by
// per-block partial stores to pbuf (= d_out scratch, overwritten by pass2).
__global__ __launch_bounds__(256, 4) void pass1_stats(
    const float* __restrict__ x0, const float* __restrict__ bg,
    const float* __restrict__ ws, float* __restrict__ pbuf)
{
    __shared__ __align__(16) float4 xs4[1600];            // 25600 B
    __shared__ __align__(16) unsigned a_fm32[3584];       // 14336 B
    const float* xs = (const float*)xs4;
    const bf16x8* afp = (const bf16x8*)a_fm32;

    int tid = threadIdx.x;
    int lane = tid & 63, w = tid >> 6;
    int l15 = lane & 15, q = lane >> 4;
    int d = w * 16 + l15;

    const unsigned short* Wbf = (const unsigned short*)(ws + WS_WBF);
    bf16x8 bfrag0, bfrag1;
    #pragma unroll
    for (int j = 0; j < 8; ++j) {
        bfrag0[j] = (short)Wbf[(q * 8 + j) * 64 + d];
        bfrag1[j] = (short)Wbf[(32 + q * 8 + j) * 64 + d];
    }
    float breg = bg[d];

    unsigned gmr[28];
    load_gmr((const unsigned*)ws + WS_GM, gmr, lane, w);

    float sums[7], sqs[7];
    #pragma unroll
    for (int t = 0; t < 7; ++t) { sums[t] = 0.f; sqs[t] = 0.f; }

    #pragma unroll 1
    for (int st = 0; st < 4; ++st) {
        int r0 = blockIdx.x * 16 + st * 4;
        int n  = r0 / 300;
        int t0 = r0 - n * 300;          // 4 | 300 -> n uniform over the 4 rows
        const float* xwin = x0 + (size_t)n * 480000 + t0 * 25;

        stage_xs(xwin, xs4, tid);
        __syncthreads();
        build_afm(xs, a_fm32, gmr, lane, w);
        __syncthreads();

        #pragma unroll
        for (int t = 0; t < 7; ++t) {
            bf16x8 a0 = afp[(t * 2 + 0) * 64 + lane];
            bf16x8 a1 = afp[(t * 2 + 1) * 64 + lane];
            f32x4 acc = {0.f, 0.f, 0.f, 0.f};
            acc = __builtin_amdgcn_mfma_f32_16x16x32_bf16(a0, bfrag0, acc, 0, 0, 0);
            acc = __builtin_amdgcn_mfma_f32_16x16x32_bf16(a1, bfrag1, acc, 0, 0, 0);
            #pragma unroll
            for (int r = 0; r < 4; ++r) {
                float y = acc[r] + breg;
                sums[t] += y;
                sqs[t]   = fmaf(y, y, sqs[t]);
            }
        }
        __syncthreads();   // a_fm + xs reads done before next window overwrites
    }

    // per-block partials, non-atomic, nontemporal (read once by stats_reduce)
    float* pout = pbuf + (size_t)blockIdx.x * 3200;
    #pragma unroll
    for (int t = 0; t < 7; ++t) {
        int v = t * 4 + q;              // C-layout: row quad == v within tile
        if (v < V_) {
            __builtin_nontemporal_store(sums[t], &pout[v * 64 + d]);
            __builtin_nontemporal_store(sqs[t],  &pout[1600 + v * 64 + d]);
        }
    }
}

// ---------- pass 2: recompute y, shift_out, BN affine, residual, ReLU ----------
__global__ __launch_bounds__(256, 4) void pass2_out(
    const float* __restrict__ x0, const float* __restrict__ bg,
    const float* __restrict__ ws, float* __restrict__ out)
{
    // xs (25600 B) and y_lds (25600 B) are time-disjoint -> union. +a_fm 14336.
    __shared__ __align__(16) char smem[25600 + 14336];    // 39936 B
    float4* xs4   = (float4*)smem;
    const float* xs = (const float*)smem;
    float* y_lds  = (float*)smem;                          // [d][dt*25 + v]
    unsigned* a_fm32 = (unsigned*)(smem + 25600);
    const bf16x8* afp = (const bf16x8*)a_fm32;

    int tid = threadIdx.x;
    int lane = tid & 63, w = tid >> 6;
    int l15 = lane & 15, q = lane >> 4;
    int d = w * 16 + l15;

    const unsigned short* Wbf = (const unsigned short*)(ws + WS_WBF);
    bf16x8 bfrag0, bfrag1;
    #pragma unroll
    for (int j = 0; j < 8; ++j) {
        bfrag0[j] = (short)Wbf[(q * 8 + j) * 64 + d];
        bfrag1[j] = (short)Wbf[(32 + q * 8 + j) * 64 + d];
    }
    float breg = bg[d];

    unsigned gmr[28];
    load_gmr((const unsigned*)ws + WS_GM, gmr, lane, w);

    int r0 = blockIdx.x * 4;
    int n  = r0 / 300;
    int t0 = r0 - n * 300;
    const float* xwin = x0 + (size_t)n * 480000 + t0 * 25;

    stage_xs(xwin, xs4, tid);
    __syncthreads();
    build_afm(xs, a_fm32, gmr, lane, w);
    __syncthreads();                    // xs dead from here; y_lds takes over

    #pragma unroll
    for (int t = 0; t < 7; ++t) {
        bf16x8 a0 = afp[(t * 2 + 0) * 64 + lane];
        bf16x8 a1 = afp[(t * 2 + 1) * 64 + lane];
        f32x4 acc = {0.f, 0.f, 0.f, 0.f};
        acc = __builtin_amdgcn_mfma_f32_16x16x32_bf16(a0, bfrag0, acc, 0, 0, 0);
        acc = __builtin_amdgcn_mfma_f32_16x16x32_bf16(a1, bfrag1, acc, 0, 0, 0);
        int v = t * 4 + q;
        if (v < V_) {
            // y[v, dt=r, d]: bank stride 4 per l15, exact 2-way across wave: free
            #pragma unroll
            for (int r = 0; r < 4; ++r)
                y_lds[d * 100 + r * 25 + v] = acc[r] + breg;
        }
    }
    __syncthreads();

    const float* scp = ws + WS_SCALE;
    const float* shp = ws + WS_SHIFT;
    const int*   vpp = (const int*)ws + WS_VP;
    #pragma unroll
    for (int i = 0; i < 25; ++i) {        // 25*256 = 6400 outputs
        int e   = i * 256 + tid;
        int dd  = e / 100;
        int rem = e - dd * 100;
        int dt  = rem / 25;
        int v   = rem - dt * 25;
        int kk  = dd * 25 + v;            // tables in output order: coalesced
        int jj  = vpp[kk];
        float z = y_lds[(jj & 63) * 100 + dt * 25 + (jj >> 6)];
        int ga  = (n * 64 + dd) * 7500 + (t0 + dt) * 25 + v;
        float val = fmaf(z, scp[kk], shp[kk]) + x0[ga];   // residual: L2-warm
        __builtin_nontemporal_store(fmaxf(val, 0.f), &out[ga]);
    }
}

extern "C" void kernel_launch(void* const* d_in, const int* in_sizes, int n_in,
                              void* d_out, int out_size, void* d_ws, size_t ws_size,
                              hipStream_t stream)
{
    const float* x0    = (const float*)d_in[0];
    const float* fm    = (const float*)d_in[1];
    const float* W     = (const float*)d_in[2];
    const float* b     = (const float*)d_in[3];
    const float* gamma = (const float*)d_in[4];
    const float* beta  = (const float*)d_in[5];
    const int*   s_in  = (const int*)d_in[6];
    const int*   s_out = (const int*)d_in[7];
    float* out = (float*)d_out;
    float* ws  = (float*)d_ws;

    prep_tables<<<16, 256, 0, stream>>>(fm, W, s_in, ws);
    // pass1 scribbles partials into d_out; pass2 fully overwrites it afterwards.
    pass1_stats<<<P1_BLOCKS, 256, 0, stream>>>(x0, b, ws, out);
    stats_reduce<<<200, 256, 0, stream>>>(out, ws);
    prep_scale_kernel<<<7, 256, 0, stream>>>(gamma, beta, s_out, ws);
    pass2_out<<<R_ / 4, 256, 0, stream>>>(x0, b, ws, out);
}

// Round 4
// 273.043 us; speedup vs baseline: 1.3324x; 1.1343x over previous
//
#include <hip/hip_runtime.h>
#include <math.h>

// Problem constants
#define V_ 25
#define C_ 64
#define D_ 64
#define N_ 64
#define T_ 300
#define R_ (N_*T_)      // 19200 rows
#define K_ (V_*C_)      // 1600
#define BN_EPS 1e-5f

// Workspace layout (4-byte units) — total 26048 f32 = 104 KB
#define WS_GM    0       // (bf16(mask)<<16) | lds_off, k order       [1600] u32
#define WS_SUM   1600    // sum_y per (v,d) flat jj                   [1600] f32
#define WS_SQ    3200    // sumsq_y per (v,d) flat jj (contig!)       [1600] f32
#define WS_WBF   4800    // W as bf16                                 [4096] u16 = 2048 f32
#define WS_SC2   6848    // BN scale, rem-order e = dd*100+rem        [6400] f32
#define WS_SH2   13248   // BN shift, rem-order                      [6400] f32
#define WS_YO    19648   // precomputed y_lds offset, rem-order      [6400] u32

// pass1: persistent blocks, double-buffered window pipeline.
#define P1_GRID  512     // each block processes windows bid, bid+512, ... (9-10)
#define NWIN     4800    // R_/4

using bf16x8 = __attribute__((ext_vector_type(8))) short;
using f32x4  = __attribute__((ext_vector_type(4))) float;
using i32x4  = __attribute__((ext_vector_type(4))) int;

__device__ __forceinline__ unsigned short f2bf(float f) {
    unsigned u = __float_as_uint(f);
    return (unsigned short)((u + 0x7FFFu + ((u >> 16) & 1u)) >> 16);
}

// async global->LDS, 16B per active lane. Dest must be uniform-base + lane*16
// (holds for all call sites: lds index = i*256 + w*64 + lane).
__device__ __forceinline__ void gload16(const void* g, void* l) {
    __builtin_amdgcn_global_load_lds(
        (const __attribute__((address_space(1))) void*)g,
        (__attribute__((address_space(3))) void*)l, 16, 0, 0);
}

// LDS-only barrier: make ds_writes visible without draining vmcnt (keeps the
// global_load_lds prefetch in flight). Rule-18 pattern: sched_barrier after wait.
__device__ __forceinline__ void barrier_lds() {
    asm volatile("s_waitcnt lgkmcnt(0)" ::: "memory");
    __builtin_amdgcn_sched_barrier(0);
    __builtin_amdgcn_s_barrier();
    __builtin_amdgcn_sched_barrier(0);
}

// ---------- prep: combined mask/offset table (k order) + bf16 W ----------
__global__ __launch_bounds__(256) void prep_tables(
    const float* __restrict__ fm, const float* __restrict__ W,
    const int* __restrict__ s_in, float* __restrict__ ws)
{
    int idx = blockIdx.x * 256 + threadIdx.x;   // 16 blocks -> 4096
    if (idx < K_) {
        int jj  = s_in[idx];
        int off = (jj & 63) * 100 + (jj >> 6);          // LDS offset, fits 16 bits
        unsigned mk = (unsigned)f2bf(tanhf(fm[idx]) + 1.0f);
        ((unsigned*)ws)[WS_GM + idx] = (mk << 16) | (unsigned)off;
    }
    if (idx < C_ * D_) ((unsigned short*)(ws + WS_WBF))[idx] = f2bf(W[idx]);
}

// ---------- reduce per-block partials (from d_out scratch) into WS_SUM/WS_SQ ----
// grid 200 x 256: block handles 16 columns; 16-way row split x 32 rows each.
__global__ __launch_bounds__(256) void stats_reduce(
    const float* __restrict__ pbuf, float* __restrict__ ws)
{
    __shared__ float red[256];
    int jq = threadIdx.x & 15;
    int bq = threadIdx.x >> 4;              // 0..15
    int j  = blockIdx.x * 16 + jq;          // 200*16 = 3200 columns
    const float* p = pbuf + (size_t)(bq * 32) * 3200 + j;
    float s = 0.f;
    #pragma unroll 8
    for (int k = 0; k < 32; ++k)
        s += p[(size_t)k * 3200];
    red[threadIdx.x] = s;
    __syncthreads();
    if (bq < 8) red[threadIdx.x] += red[threadIdx.x + 128];
    __syncthreads();
    if (bq < 4) red[threadIdx.x] += red[threadIdx.x + 64];
    __syncthreads();
    if (bq < 2) red[threadIdx.x] += red[threadIdx.x + 32];
    __syncthreads();
    if (bq == 0) ws[WS_SUM + j] = red[jq] + red[jq + 16];
}

// ---------- prep: BN scale/shift/yoff tables in OUTPUT-ELEMENT (rem) order ----
// e = dd*100 + rem, rem = dt*25 + v. yoff = full y_lds read offset.
__global__ __launch_bounds__(256) void prep_scale_kernel(
    const float* __restrict__ gamma, const float* __restrict__ beta,
    const int* __restrict__ s_out, float* __restrict__ ws)
{
    int e = blockIdx.x * 256 + threadIdx.x;     // 25 blocks -> 6400
    if (e < 6400) {
        int dd  = e / 100;
        int rem = e - dd * 100;
        int dt  = rem / 25;
        int v   = rem - dt * 25;
        int k   = v * 64 + dd;
        int jj  = s_out[k];
        float mean = ws[WS_SUM + jj] * (1.0f / (float)R_);
        float var  = fmaf(-mean, mean, ws[WS_SQ + jj] * (1.0f / (float)R_));
        float inv  = rsqrtf(var + BN_EPS);
        float sc   = gamma[k] * inv;
        ws[WS_SC2 + e] = sc;
        ws[WS_SH2 + e] = beta[k] - mean * sc;
        ((unsigned*)ws)[WS_YO + e] = (unsigned)((jj & 63) * 100 + dt * 25 + (jj >> 6));
    }
}

// window base pointer: wi in [0, 4800)
__device__ __forceinline__ const float* win_ptr(const float* x0, int wi) {
    int r0 = wi * 4;
    int n  = r0 / 300;
    int t0 = r0 - n * 300;          // t0 % 4 == 0
    return x0 + (size_t)n * 480000 + t0 * 25;
}

// Issue the 4-row window stage as async global->LDS (1600 x 16B).
// lds dest = base + idx*16 with idx = i*256+tid -> uniform base + lane*16. Guards
// are wave-uniform (idx<1600 <=> i*4+w<25).
__device__ __forceinline__ void issue_stage(
    const float* __restrict__ xwin, float4* dst, const int gOff[7], int tid)
{
    const float4* s4 = (const float4*)xwin;
    #pragma unroll
    for (int i = 0; i < 7; ++i) {
        int idx = i * 256 + tid;
        if (idx < 1600)
            gload16(s4 + gOff[i], dst + idx);
    }
}

// Preload this thread's 28 gather-table entries (same for every window).
__device__ __forceinline__ void load_gmr(
    const unsigned* __restrict__ gmt, unsigned gmr[28], int lane, int w)
{
    int jw = lane & 3;
    int vh = lane >> 4;             // m>>2 where m=lane>>2
    #pragma unroll
    for (int i = 0; i < 14; ++i) {
        int combo = i * 4 + w;      // (T,q2)
        int T  = combo >> 2;
        int q2 = combo & 3;
        int t  = T >> 1;
        int c0 = (T & 1) * 32 + q2 * 8 + jw * 2;
        int v  = t * 4 + vh;
        int kb = (v < V_) ? (v * 64 + c0) : c0;   // clamp padded rows
        gmr[2 * i]     = gmt[kb];
        gmr[2 * i + 1] = gmt[kb + 1];
    }
}

// Build fragment-major bf16 A buffer from staged xs (verified layout).
__device__ __forceinline__ void build_afm(
    const float* xs, unsigned* a_fm32, const unsigned gmr[28], int lane, int w)
{
    int m  = lane >> 2;
    int jw = lane & 3;
    int dt = m & 3;
    #pragma unroll
    for (int i = 0; i < 14; ++i) {
        int combo = i * 4 + w;
        int T  = combo >> 2;
        int q2 = combo & 3;
        unsigned g0 = gmr[2 * i], g1 = gmr[2 * i + 1];
        float m0 = __uint_as_float(g0 & 0xFFFF0000u);
        float m1 = __uint_as_float(g1 & 0xFFFF0000u);
        float f0 = xs[(g0 & 0xFFFFu) + dt * 25] * m0;
        float f1 = xs[(g1 & 0xFFFFu) + dt * 25] * m1;
        a_fm32[(T * 64 + q2 * 16 + m) * 4 + jw] =
            (unsigned)f2bf(f0) | ((unsigned)f2bf(f1) << 16);
    }
}

// ---------- pass 1: BN statistics, persistent double-buffered pipeline ----------
__global__ __launch_bounds__(256) void pass1_stats(
    const float* __restrict__ x0, const float* __restrict__ bg,
    const float* __restrict__ ws, float* __restrict__ pbuf)
{
    __shared__ __align__(16) float4 xs2[2][1600];         // 51200 B
    __shared__ __align__(16) unsigned a_fm32[3584];       // 14336 B -> 64 KB total
    const bf16x8* afp = (const bf16x8*)a_fm32;

    int tid = threadIdx.x;
    int lane = tid & 63, w = tid >> 6;
    int l15 = lane & 15, q = lane >> 4;
    int d = w * 16 + l15;

    const unsigned short* Wbf = (const unsigned short*)(ws + WS_WBF);
    bf16x8 bfrag0, bfrag1;
    #pragma unroll
    for (int j = 0; j < 8; ++j) {
        bfrag0[j] = (short)Wbf[(q * 8 + j) * 64 + d];
        bfrag1[j] = (short)Wbf[(32 + q * 8 + j) * 64 + d];
    }
    float breg = bg[d];

    unsigned gmr[28];
    load_gmr((const unsigned*)ws + WS_GM, gmr, lane, w);

    int gOff[7];
    #pragma unroll
    for (int i = 0; i < 7; ++i) {
        int idx = i * 256 + tid;
        int c = idx / 25;
        int r = idx - c * 25;
        gOff[i] = c * 1875 + r;
    }

    float sums[7], sqs[7];
    #pragma unroll
    for (int t = 0; t < 7; ++t) { sums[t] = 0.f; sqs[t] = 0.f; }

    int wi = blockIdx.x;
    issue_stage(win_ptr(x0, wi), xs2[0], gOff, tid);      // prologue prefetch
    int cur = 0;

    while (true) {
        __syncthreads();              // drains vmcnt: xs2[cur] landed; a_fm free
        int nwi = wi + P1_GRID;
        if (nwi < NWIN)               // prefetch next window into other buffer
            issue_stage(win_ptr(x0, nwi), xs2[cur ^ 1], gOff, tid);

        build_afm((const float*)xs2[cur], a_fm32, gmr, lane, w);
        barrier_lds();                // a_fm visible; prefetch stays in flight

        #pragma unroll
        for (int t = 0; t < 7; ++t) {
            bf16x8 a0 = afp[(t * 2 + 0) * 64 + lane];
            bf16x8 a1 = afp[(t * 2 + 1) * 64 + lane];
            f32x4 acc = {0.f, 0.f, 0.f, 0.f};
            acc = __builtin_amdgcn_mfma_f32_16x16x32_bf16(a0, bfrag0, acc, 0, 0, 0);
            acc = __builtin_amdgcn_mfma_f32_16x16x32_bf16(a1, bfrag1, acc, 0, 0, 0);
            #pragma unroll
            for (int r = 0; r < 4; ++r) {
                float y = acc[r] + breg;
                sums[t] += y;
                sqs[t]   = fmaf(y, y, sqs[t]);
            }
        }
        if (nwi >= NWIN) break;
        wi = nwi; cur ^= 1;
    }

    // per-block partials, non-atomic, nontemporal (read once by stats_reduce)
    float* pout = pbuf + (size_t)blockIdx.x * 3200;
    #pragma unroll
    for (int t = 0; t < 7; ++t) {
        int v = t * 4 + q;
        if (v < V_) {
            __builtin_nontemporal_store(sums[t], &pout[v * 64 + d]);
            __builtin_nontemporal_store(sqs[t],  &pout[1600 + v * 64 + d]);
        }
    }
}

// ---------- pass 2: recompute y, shift_out, BN affine, residual, ReLU ----------
// LDS 51200 B -> 3 blocks/CU. xs stays alive for the residual; y overlays a_fm
// (A fragments hoisted to registers before the overwrite).
__global__ __launch_bounds__(256, 3) void pass2_out(
    const float* __restrict__ x0, const float* __restrict__ bg,
    const float* __restrict__ ws, float* __restrict__ out)
{
    __shared__ __align__(16) float4 xs4[1600];            // 25600 B, alive all kernel
    __shared__ __align__(16) float  yu[6400];             // 25600 B: a_fm then y
    const float* xs = (const float*)xs4;
    unsigned* a_fm32 = (unsigned*)yu;
    const bf16x8* afp = (const bf16x8*)yu;
    float* y_lds = yu;

    int tid = threadIdx.x;
    int lane = tid & 63, w = tid >> 6;
    int l15 = lane & 15, q = lane >> 4;
    int d = w * 16 + l15;

    int r0 = blockIdx.x * 4;
    int n  = r0 / 300;
    int t0 = r0 - n * 300;

    int gOff[7];
    #pragma unroll
    for (int i = 0; i < 7; ++i) {
        int idx = i * 256 + tid;
        int c = idx / 25;
        int r = idx - c * 25;
        gOff[i] = c * 1875 + r;
    }
    issue_stage(x0 + (size_t)n * 480000 + t0 * 25, xs4, gOff, tid);  // async

    // overlap staging flight with table/fragment loads
    const unsigned short* Wbf = (const unsigned short*)(ws + WS_WBF);
    bf16x8 bfrag0, bfrag1;
    #pragma unroll
    for (int j = 0; j < 8; ++j) {
        bfrag0[j] = (short)Wbf[(q * 8 + j) * 64 + d];
        bfrag1[j] = (short)Wbf[(32 + q * 8 + j) * 64 + d];
    }
    float breg = bg[d];
    unsigned gmr[28];
    load_gmr((const unsigned*)ws + WS_GM, gmr, lane, w);

    __syncthreads();                    // stage landed
    build_afm(xs, a_fm32, gmr, lane, w);
    __syncthreads();                    // a_fm ready

    bf16x8 af[14];                      // hoist A fragments: a_fm region dies here
    #pragma unroll
    for (int t2 = 0; t2 < 14; ++t2)
        af[t2] = afp[t2 * 64 + lane];
    __syncthreads();                    // all reads done -> safe to overwrite with y

    #pragma unroll
    for (int t = 0; t < 7; ++t) {
        f32x4 acc = {0.f, 0.f, 0.f, 0.f};
        acc = __builtin_amdgcn_mfma_f32_16x16x32_bf16(af[2 * t],     bfrag0, acc, 0, 0, 0);
        acc = __builtin_amdgcn_mfma_f32_16x16x32_bf16(af[2 * t + 1], bfrag1, acc, 0, 0, 0);
        int v = t * 4 + q;
        if (v < V_) {
            #pragma unroll
            for (int r = 0; r < 4; ++r)
                y_lds[d * 100 + r * 25 + v] = acc[r] + breg;
        }
    }
    __syncthreads();                    // y ready

    // output: 1600 float4. Tables in rem-order -> fully coalesced f4 loads;
    // residual comes from the staged window in LDS (xs[dd*100+rem] == x0[ga]).
    const f32x4* sc4 = (const f32x4*)(ws + WS_SC2);
    const f32x4* sh4 = (const f32x4*)(ws + WS_SH2);
    const i32x4* yo4 = (const i32x4*)((const int*)ws + WS_YO);
    const f32x4* rs4 = (const f32x4*)xs;
    float* outbase = out + (size_t)n * 480000 + t0 * 25;
    #pragma unroll
    for (int i = 0; i < 7; ++i) {
        int idx = i * 256 + tid;
        if (idx < 1600) {
            int dd  = idx / 25;
            int pos = idx - dd * 25;
            f32x4 sc = sc4[idx];
            f32x4 sh = sh4[idx];
            i32x4 yo = yo4[idx];
            f32x4 rs = rs4[idx];
            f32x4 o;
            o[0] = fmaxf(fmaf(y_lds[yo[0]], sc[0], sh[0]) + rs[0], 0.f);
            o[1] = fmaxf(fmaf(y_lds[yo[1]], sc[1], sh[1]) + rs[1], 0.f);
            o[2] = fmaxf(fmaf(y_lds[yo[2]], sc[2], sh[2]) + rs[2], 0.f);
            o[3] = fmaxf(fmaf(y_lds[yo[3]], sc[3], sh[3]) + rs[3], 0.f);
            __builtin_nontemporal_store(o, (f32x4*)(outbase + dd * 7500) + pos);
        }
    }
}

extern "C" void kernel_launch(void* const* d_in, const int* in_sizes, int n_in,
                              void* d_out, int out_size, void* d_ws, size_t ws_size,
                              hipStream_t stream)
{
    const float* x0    = (const float*)d_in[0];
    const float* fm    = (const float*)d_in[1];
    const float* W     = (const float*)d_in[2];
    const float* b     = (const float*)d_in[3];
    const float* gamma = (const float*)d_in[4];
    const float* beta  = (const float*)d_in[5];
    const int*   s_in  = (const int*)d_in[6];
    const int*   s_out = (const int*)d_in[7];
    float* out = (float*)d_out;
    float* ws  = (float*)d_ws;

    prep_tables<<<16, 256, 0, stream>>>(fm, W, s_in, ws);
    // pass1 scribbles partials into d_out; pass2 fully overwrites it afterwards.
    pass1_stats<<<P1_GRID, 256, 0, stream>>>(x0, b, ws, out);
    stats_reduce<<<200, 256, 0, stream>>>(out, ws);
    prep_scale_kernel<<<25, 256, 0, stream>>>(gamma, beta, s_out, ws);
    pass2_out<<<NWIN, 256, 0, stream>>>(x0, b, ws, out);
}